// Round 4
// baseline (38.182 us; speedup 1.0000x reference)
//
#include <hip/hip_runtime.h>

// GraphSAGE encoder forward, v4: TWO simple kernels (split structure).
//  v1 25.76us fused serial;  v2 40.2us (W-duplication regression);
//  v3 33.1us (over-complex fused pipeline, register pressure).
//  v4: A) gather/aggregate -> X[8192][256] f32 in d_ws (max MLP, BW-bound)
//      B) X @ W[256][128] + b, swish (K-split, W read once per block half)
//
// Inputs: emb f32[1M,128], neigh_w f32[8192,10], W f32[256,128], b f32[128],
//         nodes i32[8192], neigh_ids i32[8192,10]. Out f32[8192,128].

#define B_NODES 8192
#define K_NEIGH 10
#define FDIM 128
#define EDIM 128

// ---------------- Kernel A: gather + weighted aggregate ---------------------
// half-wave (32 lanes) per node; lane covers float4 (d0..d0+3).
__global__ __launch_bounds__(256) void sage_gather(
    const float* __restrict__ emb,
    const float* __restrict__ neigh_w,
    const int*   __restrict__ nodes,
    const int*   __restrict__ neigh_ids,
    float* __restrict__ X)
{
    const int tid  = threadIdx.x;
    const int half = tid >> 5;                 // 0..7 -> node within block
    const int d0   = (tid & 31) * 4;
    const int n    = blockIdx.x * 8 + half;    // 0..8191

    // metadata: uniform within half-wave -> L1 broadcast
    const int*   ip = neigh_ids + n * K_NEIGH;
    const float* wp = neigh_w  + n * K_NEIGH;

    int ids[K_NEIGH];
#pragma unroll
    for (int k = 0; k < K_NEIGH; ++k) ids[k] = ip[k];
    const int sid = nodes[n];

    float wk[K_NEIGH], wsum = 0.f;
#pragma unroll
    for (int k = 0; k < K_NEIGH; ++k) { wk[k] = wp[k]; wsum += wk[k]; }
    const float inv = 1.f / wsum;

    const float4 sv = *reinterpret_cast<const float4*>(&emb[(size_t)sid * FDIM + d0]);

    float4 a = make_float4(0.f, 0.f, 0.f, 0.f);
#pragma unroll
    for (int k = 0; k < K_NEIGH; ++k) {
        const float4 v = *reinterpret_cast<const float4*>(&emb[(size_t)ids[k] * FDIM + d0]);
        a.x = fmaf(wk[k], v.x, a.x);
        a.y = fmaf(wk[k], v.y, a.y);
        a.z = fmaf(wk[k], v.z, a.z);
        a.w = fmaf(wk[k], v.w, a.w);
    }

    float* Xr = X + (size_t)n * (2 * FDIM);
    *reinterpret_cast<float4*>(&Xr[d0]) = sv;
    *reinterpret_cast<float4*>(&Xr[FDIM + d0]) =
        make_float4(a.x * inv, a.y * inv, a.z * inv, a.w * inv);
}

// ---------------- Kernel B: X[8192,256] @ W[256,128] + b, swish -------------
// 256 threads: e = tid&127 (output col), h = tid>>7 (K-half).
// Each 128-thread group streams its half of W exactly once per block.
#define MT 16   // rows per block
__global__ __launch_bounds__(256) void sage_gemm(
    const float* __restrict__ X,
    const float* __restrict__ Wm,
    const float* __restrict__ bias,
    float* __restrict__ out)
{
    __shared__ __align__(16) float Xs[MT][2 * FDIM];   // 16 KB
    __shared__ float red[MT][EDIM];                    // 8 KB

    const int tid = threadIdx.x;
    const int m0  = blockIdx.x * MT;

    // stage X tile: 1024 float4 chunks, coalesced
#pragma unroll
    for (int i = 0; i < 4; ++i) {
        const int idx = tid + i * 256;         // 0..1023
        const int r   = idx >> 6;              // row 0..15
        const int c   = idx & 63;              // float4 col 0..63
        reinterpret_cast<float4*>(&Xs[r][0])[c] =
            reinterpret_cast<const float4*>(&X[(size_t)(m0 + r) * (2 * FDIM)])[c];
    }
    __syncthreads();

    const int e = tid & (EDIM - 1);
    const int h = tid >> 7;

    float acc[MT];
#pragma unroll
    for (int r = 0; r < MT; ++r) acc[r] = 0.f;

    const float* Wp = Wm + (size_t)(h * FDIM) * EDIM + e;
#pragma unroll 2
    for (int d = 0; d < FDIM; d += 4) {
        // coalesced scalar W loads: lane -> e, 4B/lane
        const float w0 = Wp[(d + 0) * EDIM];
        const float w1 = Wp[(d + 1) * EDIM];
        const float w2 = Wp[(d + 2) * EDIM];
        const float w3 = Wp[(d + 3) * EDIM];
#pragma unroll
        for (int r = 0; r < MT; ++r) {
            // wave-uniform address -> LDS broadcast
            const float4 xv = *reinterpret_cast<const float4*>(&Xs[r][h * FDIM + d]);
            acc[r] = fmaf(xv.x, w0, fmaf(xv.y, w1, fmaf(xv.z, w2, fmaf(xv.w, w3, acc[r]))));
        }
    }

    // cross-group reduce: each group writes partials for the OTHER group's rows
    {
        const int rbase = (1 - h) * (MT / 2);
#pragma unroll
        for (int r = 0; r < MT / 2; ++r) red[rbase + r][e] = acc[rbase + r];
    }
    __syncthreads();

    // each group finalizes its own rows
    {
        const int rbase = h * (MT / 2);
        const float bv = bias[e];
#pragma unroll
        for (int r = 0; r < MT / 2; ++r) {
            const float v = acc[rbase + r] + red[rbase + r][e] + bv;
            out[(size_t)(m0 + rbase + r) * EDIM + e] = v / (1.f + __expf(-v));
        }
    }
}

extern "C" void kernel_launch(void* const* d_in, const int* in_sizes, int n_in,
                              void* d_out, int out_size, void* d_ws, size_t ws_size,
                              hipStream_t stream) {
    const float* emb       = (const float*)d_in[0];
    const float* neigh_w   = (const float*)d_in[1];
    const float* Wm        = (const float*)d_in[2];
    const float* bias      = (const float*)d_in[3];
    const int*   nodes     = (const int*)d_in[4];
    const int*   neigh_ids = (const int*)d_in[5];
    float* out = (float*)d_out;
    float* X   = (float*)d_ws;                 // 8192*256 f32 = 8 MB scratch

    sage_gather<<<dim3(B_NODES / 8), dim3(256), 0, stream>>>(
        emb, neigh_w, nodes, neigh_ids, X);
    sage_gemm<<<dim3(B_NODES / MT), dim3(256), 0, stream>>>(
        X, Wm, bias, out);
}

// Round 5
// 16.399 us; speedup vs baseline: 2.3283x; 2.3283x over previous
//
#include <hip/hip_runtime.h>

// GraphSAGE encoder forward, v5: fused, MFMA (bf16) GEMM.
//  v1 25.8us (broadcast-LDS GEMM: ~512 ds_read_b128/wave -> LDS-issue-bound ~10us
//             + serial latency-bound gather ~15us)
//  v2 40.2us (W float4 duplication, 1GB L2);  v3 33.1us (overpipelined fused);
//  v4 38.2us (split kernels, same LDS-bound GEMM + 2nd-launch cost).
//  v5: GEMM via mfma_f32_16x16x32_bf16. Per wave: 8 swizzled ds_read_b128
//      (A-frags) + 128 coalesced scalar W loads (L2-resident) + 16 MFMA.
//      LDS issue count drops 64x. Single sync. bf16 error ~1e-2 < 7.7e-2 thr.
//
// Inputs: emb f32[1M,128], neigh_w f32[8192,10], W f32[256,128], b f32[128],
//         nodes i32[8192], neigh_ids i32[8192,10]. Out f32[8192,128].

#define B_NODES 8192
#define K_NEIGH 10
#define FDIM 128
#define EDIM 128
#define NPB 16
#define THREADS 256

typedef __attribute__((ext_vector_type(8))) short short8v;  // 8 bf16 (4 VGPR)
typedef __attribute__((ext_vector_type(4))) float float4v;  // mfma acc

// XOR-swizzle byte addr: flip bits 4..6 by row (rows are 512B). Breaks the
// 16-way bank conflict of stride-512B A-frag reads; write side uses the same
// map (both-sides-or-neither).
__device__ __forceinline__ int swz(int byte) {
    return byte ^ (((byte >> 9) & 7) << 4);
}

// f32 -> bf16 bits, round-to-nearest-even
__device__ __forceinline__ short f2bf(float f) {
    unsigned u = __builtin_bit_cast(unsigned, f);
    u += 0x7FFFu + ((u >> 16) & 1u);
    return (short)(u >> 16);
}

__global__ __launch_bounds__(THREADS, 2) void sage_fused(
    const float* __restrict__ emb,
    const float* __restrict__ neigh_w,
    const float* __restrict__ Wm,
    const float* __restrict__ bias,
    const int*   __restrict__ nodes,
    const int*   __restrict__ neigh_ids,
    float* __restrict__ out)
{
    __shared__ __align__(16) short x_lds[NPB * 2 * FDIM];   // bf16 X tile, 8 KB
    char* xb = (char*)x_lds;

    const int tid = threadIdx.x;
    const int nb0 = blockIdx.x * NPB;

    // ================= Phase 1: gather + aggregate -> bf16 X tile ===========
    // half-wave (32 lanes) per 2 nodes; lane covers float4 (4 dims).
    {
        const int hw  = tid >> 5;          // 0..7
        const int l32 = tid & 31;
        const int d0  = l32 * 4;

        const int nA = hw * 2, nB = nA + 1;
        const int gA = nb0 + nA, gB = nb0 + nB;

        // metadata for BOTH nodes first (independent, go in flight together)
        const int sidA = nodes[gA];
        const int sidB = nodes[gB];
        int idsA[K_NEIGH], idsB[K_NEIGH];
        float wA[K_NEIGH], wB[K_NEIGH];
#pragma unroll
        for (int k = 0; k < K_NEIGH; ++k) idsA[k] = neigh_ids[gA * K_NEIGH + k];
#pragma unroll
        for (int k = 0; k < K_NEIGH; ++k) idsB[k] = neigh_ids[gB * K_NEIGH + k];
        float wsA = 0.f, wsB = 0.f;
#pragma unroll
        for (int k = 0; k < K_NEIGH; ++k) { wA[k] = neigh_w[gA * K_NEIGH + k]; wsA += wA[k]; }
#pragma unroll
        for (int k = 0; k < K_NEIGH; ++k) { wB[k] = neigh_w[gB * K_NEIGH + k]; wsB += wB[k]; }
        const float invA = 1.f / wsA, invB = 1.f / wsB;

        // ---- node A rows ----
        {
            const float4 sv = *reinterpret_cast<const float4*>(&emb[(size_t)sidA * FDIM + d0]);
            float4 a = make_float4(0.f, 0.f, 0.f, 0.f);
#pragma unroll
            for (int k = 0; k < K_NEIGH; ++k) {
                const float4 v = *reinterpret_cast<const float4*>(&emb[(size_t)idsA[k] * FDIM + d0]);
                a.x = fmaf(wA[k], v.x, a.x); a.y = fmaf(wA[k], v.y, a.y);
                a.z = fmaf(wA[k], v.z, a.z); a.w = fmaf(wA[k], v.w, a.w);
            }
            ushort4 s4, g4;
            s4.x = (unsigned short)f2bf(sv.x); s4.y = (unsigned short)f2bf(sv.y);
            s4.z = (unsigned short)f2bf(sv.z); s4.w = (unsigned short)f2bf(sv.w);
            g4.x = (unsigned short)f2bf(a.x * invA); g4.y = (unsigned short)f2bf(a.y * invA);
            g4.z = (unsigned short)f2bf(a.z * invA); g4.w = (unsigned short)f2bf(a.w * invA);
            *reinterpret_cast<ushort4*>(xb + swz(nA * 512 + l32 * 8))       = s4;
            *reinterpret_cast<ushort4*>(xb + swz(nA * 512 + 256 + l32 * 8)) = g4;
        }
        // ---- node B rows ----
        {
            const float4 sv = *reinterpret_cast<const float4*>(&emb[(size_t)sidB * FDIM + d0]);
            float4 a = make_float4(0.f, 0.f, 0.f, 0.f);
#pragma unroll
            for (int k = 0; k < K_NEIGH; ++k) {
                const float4 v = *reinterpret_cast<const float4*>(&emb[(size_t)idsB[k] * FDIM + d0]);
                a.x = fmaf(wB[k], v.x, a.x); a.y = fmaf(wB[k], v.y, a.y);
                a.z = fmaf(wB[k], v.z, a.z); a.w = fmaf(wB[k], v.w, a.w);
            }
            ushort4 s4, g4;
            s4.x = (unsigned short)f2bf(sv.x); s4.y = (unsigned short)f2bf(sv.y);
            s4.z = (unsigned short)f2bf(sv.z); s4.w = (unsigned short)f2bf(sv.w);
            g4.x = (unsigned short)f2bf(a.x * invB); g4.y = (unsigned short)f2bf(a.y * invB);
            g4.z = (unsigned short)f2bf(a.z * invB); g4.w = (unsigned short)f2bf(a.w * invB);
            *reinterpret_cast<ushort4*>(xb + swz(nB * 512 + l32 * 8))       = s4;
            *reinterpret_cast<ushort4*>(xb + swz(nB * 512 + 256 + l32 * 8)) = g4;
        }
    }
    __syncthreads();

    // ================= Phase 2: X[16,256] @ W[256,128] via MFMA =============
    // wave w owns output cols [w*32, w*32+32): two 16x16 N-tiles.
    // A-frag: lane l -> X[row=l&15][k=(l>>4)*8 + j]  (one swizzled b128 read)
    // B-frag: lane l -> W[k=(l>>4)*8 + j][e0 + (l&15)] (8 coalesced f32 loads,
    //         L2-resident 128KB W, converted to bf16 in-register)
    // D:      lane l reg r -> out[row=(l>>4)*4 + r][e0 + (l&15)]
    {
        const int l    = tid & 63;
        const int wave = tid >> 6;
        const int lg   = l >> 4;           // k-group / row-group
        const int li   = l & 15;

        float4v acc0 = {0.f, 0.f, 0.f, 0.f};
        float4v acc1 = {0.f, 0.f, 0.f, 0.f};
        const int e0 = wave * 32;          // N-tile 0: e0, N-tile 1: e0+16

#pragma unroll
        for (int kblk = 0; kblk < 8; ++kblk) {
            const short8v a = *reinterpret_cast<const short8v*>(
                xb + swz(li * 512 + kblk * 64 + lg * 16));

            const int kb = kblk * 32 + lg * 8;
            short8v b0, b1;
#pragma unroll
            for (int j = 0; j < 8; ++j) {
                b0[j] = f2bf(Wm[(size_t)(kb + j) * EDIM + e0 + li]);
                b1[j] = f2bf(Wm[(size_t)(kb + j) * EDIM + e0 + 16 + li]);
            }
            acc0 = __builtin_amdgcn_mfma_f32_16x16x32_bf16(a, b0, acc0, 0, 0, 0);
            acc1 = __builtin_amdgcn_mfma_f32_16x16x32_bf16(a, b1, acc1, 0, 0, 0);
        }

        // epilogue: bias + swish, scalar stores (4MB total)
        const float bv0 = bias[e0 + li];
        const float bv1 = bias[e0 + 16 + li];
#pragma unroll
        for (int r = 0; r < 4; ++r) {
            const int row = nb0 + lg * 4 + r;
            float v0 = acc0[r] + bv0;
            float v1 = acc1[r] + bv1;
            out[(size_t)row * EDIM + e0 + li]      = v0 / (1.f + __expf(-v0));
            out[(size_t)row * EDIM + e0 + 16 + li] = v1 / (1.f + __expf(-v1));
        }
    }
}

extern "C" void kernel_launch(void* const* d_in, const int* in_sizes, int n_in,
                              void* d_out, int out_size, void* d_ws, size_t ws_size,
                              hipStream_t stream) {
    const float* emb       = (const float*)d_in[0];
    const float* neigh_w   = (const float*)d_in[1];
    const float* Wm        = (const float*)d_in[2];
    const float* bias      = (const float*)d_in[3];
    const int*   nodes     = (const int*)d_in[4];
    const int*   neigh_ids = (const int*)d_in[5];
    float* out = (float*)d_out;

    sage_fused<<<dim3(B_NODES / NPB), dim3(THREADS), 0, stream>>>(
        emb, neigh_w, Wm, bias, nodes, neigh_ids, out);
}